// Round 10
// baseline (162.315 us; speedup 1.0000x reference)
//
#include <hip/hip_runtime.h>

typedef unsigned short ushort_t;
typedef __bf16 bf16x8 __attribute__((ext_vector_type(8)));
typedef float f32x4 __attribute__((ext_vector_type(4)));
typedef float f32x2 __attribute__((ext_vector_type(2)));
typedef ushort_t us4 __attribute__((ext_vector_type(4)));

#define T_SOFT 32.0f
#define THRESH 0.76604444311897803f   // cos(40 deg)
#define SW 1048                       // W strip LDS row stride (bf16)
#define SA 72                         // GEMM LDS row stride (bf16)

__device__ __forceinline__ ushort_t f2bf(float f) {
  union { float f; unsigned u; } x; x.f = f;
  unsigned r = (x.u + 0x7fffu + ((x.u >> 16) & 1u)) >> 16;  // RNE
  return (ushort_t)r;
}
__device__ __forceinline__ float bf2f(ushort_t h) {
  union { unsigned u; float f; } x; x.u = ((unsigned)h) << 16; return x.f;
}

// pack 4 fp32 -> 4 bf16
__device__ __forceinline__ us4 pack4(float4 x) {
  union { unsigned u[2]; us4 h; } r;
  union { float4 f; unsigned u[4]; } a;
  a.f = x;
  r.u[0] = __builtin_amdgcn_perm(a.u[1] + 0x8000u, a.u[0] + 0x8000u, 0x07060302u);
  r.u[1] = __builtin_amdgcn_perm(a.u[3] + 0x8000u, a.u[2] + 0x8000u, 0x07060302u);
  return r.h;
}

// ---- row-stage split load/store: rows clamped, cols >= climit -> 0 ----
struct RL { float4 v[8]; };
__device__ __forceinline__ RL r_load(const float* __restrict__ src, int srs, int rowbase, int rowmax,
                                     int kbase, int climit, int tid) {
  RL o;
  int frow = tid >> 4, fk = (tid & 15) * 4;
  #pragma unroll
  for (int p = 0; p < 8; ++p) {
    int row = rowbase + frow + p * 16; if (row > rowmax) row = rowmax;
    int k = kbase + fk;
    float4 val = make_float4(0.f, 0.f, 0.f, 0.f);
    if (k < climit) val = *reinterpret_cast<const float4*>(src + (size_t)row * srs + k);
    o.v[p] = val;
  }
  return o;
}
__device__ __forceinline__ void r_store(const RL& o, ushort_t* __restrict__ dst, int tid) {
  int frow = tid >> 4, fk = (tid & 15) * 4;
  #pragma unroll
  for (int p = 0; p < 8; ++p)
    *reinterpret_cast<us4*>(dst + (size_t)(frow + p * 16) * SA + fk) = pack4(o.v[p]);
}

// ---- transpose-stage split: dst[ncol][krow] <- src[rbase+krow][nbase+ncol]; rows>=rlimit -> 0 ----
struct TL { float v[4][8]; };
__device__ __forceinline__ TL t_load(const float* __restrict__ src, int srs, int rbase, int rlimit,
                                     int nbase, int tid) {
  TL o;
  int kg = (tid >> 4) * 4, ns = (tid & 15) * 8;
  #pragma unroll
  for (int i = 0; i < 4; ++i) {
    int r = rbase + kg + i;
    float4 a = make_float4(0.f,0.f,0.f,0.f), c = make_float4(0.f,0.f,0.f,0.f);
    if (r < rlimit) {
      a = *reinterpret_cast<const float4*>(src + (size_t)r * srs + nbase + ns);
      c = *reinterpret_cast<const float4*>(src + (size_t)r * srs + nbase + ns + 4);
    }
    o.v[i][0]=a.x; o.v[i][1]=a.y; o.v[i][2]=a.z; o.v[i][3]=a.w;
    o.v[i][4]=c.x; o.v[i][5]=c.y; o.v[i][6]=c.z; o.v[i][7]=c.w;
  }
  return o;
}
__device__ __forceinline__ void t_store(const TL& o, ushort_t* __restrict__ dst, int tid) {
  int kg = (tid >> 4) * 4, ns = (tid & 15) * 8;
  #pragma unroll
  for (int j = 0; j < 8; ++j) {
    us4 w;
    w[0] = f2bf(o.v[0][j]); w[1] = f2bf(o.v[1][j]); w[2] = f2bf(o.v[2][j]); w[3] = f2bf(o.v[3][j]);
    *reinterpret_cast<us4*>(dst + (size_t)(ns + j) * SA + kg) = w;
  }
}

// ---- bf16 row-stage split ----
struct AL { bf16x8 v[4]; };
__device__ __forceinline__ AL a_load(const ushort_t* __restrict__ src, int srs, int kbase, int tid) {
  AL o;
  int hrow = tid >> 3, hk = (tid & 7) * 8;
  #pragma unroll
  for (int p = 0; p < 4; ++p)
    o.v[p] = *reinterpret_cast<const bf16x8*>(src + (size_t)(hrow + p * 32) * srs + kbase + hk);
  return o;
}
__device__ __forceinline__ void a_store(const AL& o, ushort_t* __restrict__ dst, int tid) {
  int hrow = tid >> 3, hk = (tid & 7) * 8;
  #pragma unroll
  for (int p = 0; p < 4; ++p)
    *reinterpret_cast<bf16x8*>(dst + (size_t)(hrow + p * 32) * SA + hk) = o.v[p];
}

// ---- one 128x128x64 MFMA step over staged As/Bs ----
__device__ __forceinline__ void mfma8(ushort_t* __restrict__ As, ushort_t* __restrict__ Bs,
                                      int tid, f32x4 acc[2][8]) {
  int lane = tid & 63, wv = tid >> 6;
  int l15 = lane & 15, quad = lane >> 4;
  #pragma unroll
  for (int kh = 0; kh < 2; ++kh) {
    bf16x8 af[2];
    #pragma unroll
    for (int pi = 0; pi < 2; ++pi)
      af[pi] = *reinterpret_cast<bf16x8*>(As + ((wv * 2 + pi) * 16 + l15) * SA + kh * 32 + quad * 8);
    #pragma unroll
    for (int ct = 0; ct < 8; ++ct) {
      bf16x8 bfr = *reinterpret_cast<bf16x8*>(Bs + (ct * 16 + l15) * SA + kh * 32 + quad * 8);
      acc[0][ct] = __builtin_amdgcn_mfma_f32_16x16x32_bf16(af[0], bfr, acc[0][ct], 0, 0, 0);
      acc[1][ct] = __builtin_amdgcn_mfma_f32_16x16x32_bf16(af[1], bfr, acc[1][ct], 0, 0, 0);
    }
  }
}

// ---------------- prep: gn MFMA (8) + misc (1) + ihp x16 (256) + M2T (16) + GT0 (8) = 289 ----------------
__global__ __launch_bounds__(256) void prep_k(
    const float* __restrict__ attributes, const float* __restrict__ att_g,
    ushort_t* __restrict__ gn_bf,
    const float* __restrict__ image_feats, const float* __restrict__ img_w,
    float* __restrict__ ihp,
    const float* __restrict__ proto_w, const float* __restrict__ slim_w,
    ushort_t* __restrict__ M2T, float* __restrict__ GT_part,
    const float* __restrict__ slim_b, const float* __restrict__ proto_b,
    float* __restrict__ biasG) {
  __shared__ ushort_t As[128 * SA];
  __shared__ ushort_t Bs[128 * SA];
  int b = blockIdx.x, tid = threadIdx.x;
  if (b == 8) {                 // misc: zero gn tail rows 1000..1007 + biasG
    us4 z = {0, 0, 0, 0};
    *reinterpret_cast<us4*>(gn_bf + 1000 * 128 + tid * 4) = z;
    if (tid < 128) {
      int h = tid;
      float acc = proto_b[h];
      for (int n = 0; n < 312; n += 4) {
        acc += slim_b[n + 0] * proto_w[(size_t)(312 + n) * 128 + h];
        acc += slim_b[n + 1] * proto_w[(size_t)(313 + n) * 128 + h];
        acc += slim_b[n + 2] * proto_w[(size_t)(314 + n) * 128 + h];
        acc += slim_b[n + 3] * proto_w[(size_t)(315 + n) * 128 + h];
      }
      biasG[h] = acc;
    }
    return;
  }
  int lane = tid & 63, wv = tid >> 6;
  int l15 = lane & 15, quad = lane >> 4;
  f32x4 acc[2][8];
  #pragma unroll
  for (int i = 0; i < 2; ++i)
    #pragma unroll
    for (int j = 0; j < 8; ++j) acc[i][j] = f32x4{0.f, 0.f, 0.f, 0.f};

  if (b < 8) {                  // gn: g = attributes @ att_g (K=312->320), row-normalize, bf16
    int j0 = b * 128;
    RL ra = r_load(attributes, 312, j0, 999, 0, 312, tid);
    TL tb = t_load(att_g, 128, 0, 312, 0, tid);
    for (int s = 0; s < 5; ++s) {
      if (s) __syncthreads();
      r_store(ra, As, tid);
      t_store(tb, Bs, tid);
      if (s + 1 < 5) {
        ra = r_load(attributes, 312, j0, 999, (s + 1) * 64, 312, tid);
        tb = t_load(att_g, 128, (s + 1) * 64, 312, 0, tid);
      }
      __syncthreads();
      mfma8(As, Bs, tid, acc);
    }
    // per-row sumsq: for fixed (wv,pi,quad,r) the 16 lanes (l15) x 8 ct tiles cover all 128 cols
    #pragma unroll
    for (int pi = 0; pi < 2; ++pi)
      #pragma unroll
      for (int r = 0; r < 4; ++r) {
        float ss = 0.f;
        #pragma unroll
        for (int ct = 0; ct < 8; ++ct) ss += acc[pi][ct][r] * acc[pi][ct][r];
        ss += __shfl_xor(ss, 1, 64); ss += __shfl_xor(ss, 2, 64);
        ss += __shfl_xor(ss, 4, 64); ss += __shfl_xor(ss, 8, 64);
        float inv = 1.f / fmaxf(sqrtf(ss), 1e-12f);
        int row = j0 + (wv * 2 + pi) * 16 + quad * 4 + r;
        if (row < 1000) {
          #pragma unroll
          for (int ct = 0; ct < 8; ++ct)
            gn_bf[(size_t)row * 128 + ct * 16 + l15] = f2bf(acc[pi][ct][r] * inv);
        }
      }
    return;
  }

  if (b < 265) {                // ihp split-K16 partial: b in [9,265) -> 256 blocks; K=128 (2 steps)
    int q = b - 9;
    int tile = q >> 4, kc = q & 15;
    int r0 = tile * 128, k0 = kc * 128;
    RL ra = r_load(image_feats, 2048, r0, 2047, k0, 1 << 30, tid);
    TL tb = t_load(img_w, 128, k0, 2048, 0, tid);
    #pragma unroll
    for (int s = 0; s < 2; ++s) {
      if (s) __syncthreads();
      r_store(ra, As, tid);
      t_store(tb, Bs, tid);
      if (s == 0) {
        ra = r_load(image_feats, 2048, r0, 2047, k0 + 64, 1 << 30, tid);
        tb = t_load(img_w, 128, k0 + 64, 2048, 0, tid);
      }
      __syncthreads();
      mfma8(As, Bs, tid, acc);
    }
    float* Cp = ihp + (size_t)kc * 262144;
    #pragma unroll
    for (int pi = 0; pi < 2; ++pi)
      #pragma unroll
      for (int ct = 0; ct < 8; ++ct) {
        int col = ct * 16 + l15;
        #pragma unroll
        for (int r = 0; r < 4; ++r) {
          int row = r0 + (wv * 2 + pi) * 16 + quad * 4 + r;
          Cp[(size_t)row * 128 + col] = acc[pi][ct][r];
        }
      }
    return;
  }
  if (b < 281) {                // M2T: b in [265,281) -> 16 blocks
    int c0 = (b - 265) * 128;
    TL ta = t_load(proto_w, 128, 312, 624, 0, tid);
    RL rb = r_load(slim_w, 312, c0, 2047, 0, 312, tid);
    for (int s = 0; s < 5; ++s) {
      if (s) __syncthreads();
      t_store(ta, As, tid);
      r_store(rb, Bs, tid);
      if (s + 1 < 5) {
        ta = t_load(proto_w, 128, 312 + (s + 1) * 64, 624, 0, tid);
        rb = r_load(slim_w, 312, c0, 2047, (s + 1) * 64, 312, tid);
      }
      __syncthreads();
      mfma8(As, Bs, tid, acc);
    }
    #pragma unroll
    for (int pi = 0; pi < 2; ++pi)
      #pragma unroll
      for (int ct = 0; ct < 8; ++ct) {
        int col = c0 + ct * 16 + l15;
        #pragma unroll
        for (int r = 0; r < 4; ++r) {
          int row = (wv * 2 + pi) * 16 + quad * 4 + r;
          M2T[(size_t)row * 2048 + col] = f2bf(acc[pi][ct][r]);
        }
      }
    return;
  }
  {                             // GT0: b in [281,289) -> 8 blocks; GT0[h][j] = sum_n proto_w[n][h]*attributes[j][n]
    int j0 = (b - 281) * 128;
    TL ta = t_load(proto_w, 128, 0, 312, 0, tid);
    RL rb = r_load(attributes, 312, j0, 999, 0, 312, tid);
    for (int s = 0; s < 5; ++s) {
      if (s) __syncthreads();
      t_store(ta, As, tid);
      r_store(rb, Bs, tid);
      if (s + 1 < 5) {
        ta = t_load(proto_w, 128, (s + 1) * 64, 312, 0, tid);
        rb = r_load(attributes, 312, j0, 999, (s + 1) * 64, 312, tid);
      }
      __syncthreads();
      mfma8(As, Bs, tid, acc);
    }
    #pragma unroll
    for (int pi = 0; pi < 2; ++pi)
      #pragma unroll
      for (int ct = 0; ct < 8; ++ct) {
        int col = j0 + ct * 16 + l15;
        #pragma unroll
        for (int r = 0; r < 4; ++r) {
          int row = (wv * 2 + pi) * 16 + quad * 4 + r;
          GT_part[(size_t)row * 1024 + col] = acc[pi][ct][r];
        }
      }
  }
}

// ---------------- red: img_h reduce (128, 16 chunks) + GT chunks 1..16 (128, K=128) = 256 ----------------
__global__ __launch_bounds__(256) void red_k(
    const float* __restrict__ ihp, float* __restrict__ img_h,
    const ushort_t* __restrict__ M2T, const float* __restrict__ img_proto,
    float* __restrict__ GT_part) {
  __shared__ ushort_t As[128 * SA];
  __shared__ ushort_t Bs[128 * SA];
  int b = blockIdx.x, tid = threadIdx.x;
  if (b < 128) {                // img_h[r][h] = sum_{c<16} ihp[c][r][h]
    int t = b * 256 + tid;      // 0..32767
    size_t base = (size_t)t * 8;
    #pragma unroll
    for (int g = 0; g < 2; ++g) {
      float4 s = *reinterpret_cast<const float4*>(ihp + base + g * 4);
      #pragma unroll
      for (int c = 1; c < 16; ++c) {
        float4 v = *reinterpret_cast<const float4*>(ihp + (size_t)c * 262144 + base + g * 4);
        s.x += v.x; s.y += v.y; s.z += v.z; s.w += v.w;
      }
      *reinterpret_cast<float4*>(img_h + base + g * 4) = s;
    }
    return;
  }
  int q = b - 128;              // 0..127
  int jt = q >> 4, ch = q & 15;
  int j0 = jt * 128, k0 = ch * 128;
  f32x4 acc[2][8];
  #pragma unroll
  for (int i = 0; i < 2; ++i)
    #pragma unroll
    for (int j = 0; j < 8; ++j) acc[i][j] = f32x4{0.f, 0.f, 0.f, 0.f};
  AL aa = a_load(M2T, 2048, k0, tid);
  RL rb = r_load(img_proto, 2048, j0, 999, k0, 1 << 30, tid);
  #pragma unroll
  for (int s = 0; s < 2; ++s) {
    if (s) __syncthreads();
    a_store(aa, As, tid);
    r_store(rb, Bs, tid);
    if (s == 0) {
      aa = a_load(M2T, 2048, k0 + 64, tid);
      rb = r_load(img_proto, 2048, j0, 999, k0 + 64, 1 << 30, tid);
    }
    __syncthreads();
    mfma8(As, Bs, tid, acc);
  }
  int lane = tid & 63, wv = tid >> 6;
  int l15 = lane & 15, quad = lane >> 4;
  float* dst = GT_part + (size_t)(ch + 1) * 131072;
  #pragma unroll
  for (int pi = 0; pi < 2; ++pi)
    #pragma unroll
    for (int ct = 0; ct < 8; ++ct) {
      int col = j0 + ct * 16 + l15;
      #pragma unroll
      for (int r = 0; r < 4; ++r) {
        int row = (wv * 2 + pi) * 16 + quad * 4 + r;
        dst[(size_t)row * 1024 + col] = acc[pi][ct][r];
      }
    }
}

// ---------------- gtred: GT = bf16( sum_{c<17} GT_part[c] + biasG[h] ) ----------------
__global__ __launch_bounds__(256) void gtred_k(const float* __restrict__ GT_part,
                                               const float* __restrict__ biasG,
                                               ushort_t* __restrict__ GT) {
  int t = blockIdx.x * 256 + threadIdx.x;   // 0..8191
  size_t base = (size_t)t * 16;
  int row = (int)(base >> 10);
  float bg = biasG[row];
  #pragma unroll
  for (int g = 0; g < 4; ++g) {
    float4 s = *reinterpret_cast<const float4*>(GT_part + base + g * 4);
    #pragma unroll
    for (int c = 1; c < 17; ++c) {
      float4 v = *reinterpret_cast<const float4*>(GT_part + (size_t)c * 131072 + base + g * 4);
      s.x += v.x; s.y += v.y; s.z += v.z; s.w += v.w;
    }
    s.x += bg; s.y += bg; s.z += bg; s.w += bg;
    *reinterpret_cast<us4*>(GT + base + g * 4) = pack4(s);
  }
}

// ---------------- attn6: sim -> masked exp -> ph = (W@GT^T)/rsum ; 512 threads ----------------
__global__ __launch_bounds__(512) void attn6_k(
    const ushort_t* __restrict__ gn_bf, const ushort_t* __restrict__ GT,
    float* __restrict__ ph) {
  __shared__ ushort_t W[16 * SW];
  __shared__ float rsum[16];
  __shared__ int flags[63];
  int tid = threadIdx.x;
  int i0 = blockIdx.x * 16;
  int lane = tid & 63, wv = tid >> 6;       // wv 0..7
  int l15 = lane & 15, quad = lane >> 4;
  if (tid < 63) flags[tid] = 0;
  if (tid >= 64 && tid < 80) rsum[tid - 64] = 0.f;
  if (tid < 256) W[(tid >> 4) * SW + 1008 + (tid & 15)] = 0;   // zero k-pad cols 1008..1023
  __syncthreads();

  const ushort_t* abase = gn_bf + (size_t)(i0 + l15) * 128 + quad * 8;
  bf16x8 af0 = *reinterpret_cast<const bf16x8*>(abase);
  bf16x8 af1 = *reinterpret_cast<const bf16x8*>(abase + 32);
  bf16x8 af2 = *reinterpret_cast<const bf16x8*>(abase + 64);
  bf16x8 af3 = *reinterpret_cast<const bf16x8*>(abase + 96);
  float rs[4] = {0.f, 0.f, 0.f, 0.f};
  for (int jt = wv; jt < 63; jt += 8) {
    const ushort_t* bbase = gn_bf + (size_t)(jt * 16 + l15) * 128 + quad * 8;
    f32x4 d = {0.f, 0.f, 0.f, 0.f};
    d = __builtin_amdgcn_mfma_f32_16x16x32_bf16(af0, *reinterpret_cast<const bf16x8*>(bbase),      d, 0, 0, 0);
    d = __builtin_amdgcn_mfma_f32_16x16x32_bf16(af1, *reinterpret_cast<const bf16x8*>(bbase + 32), d, 0, 0, 0);
    d = __builtin_amdgcn_mfma_f32_16x16x32_bf16(af2, *reinterpret_cast<const bf16x8*>(bbase + 64), d, 0, 0, 0);
    d = __builtin_amdgcn_mfma_f32_16x16x32_bf16(af3, *reinterpret_cast<const bf16x8*>(bbase + 96), d, 0, 0, 0);
    int hot = 0;
    #pragma unroll
    for (int r = 0; r < 4; ++r) {
      float w = 0.f;
      if (d[r] > THRESH) { w = __expf(T_SOFT * (d[r] - 1.0f)); hot = 1; }
      ushort_t wb = f2bf(w);
      W[(quad * 4 + r) * SW + jt * 16 + l15] = wb;
      rs[r] += bf2f(wb);
    }
    if (hot) flags[jt] = 1;
  }
  #pragma unroll
  for (int r = 0; r < 4; ++r) {
    float v = rs[r];
    v += __shfl_xor(v, 1, 64); v += __shfl_xor(v, 2, 64);
    v += __shfl_xor(v, 4, 64); v += __shfl_xor(v, 8, 64);
    if (l15 == 0) atomicAdd(&rsum[quad * 4 + r], v);
  }
  __syncthreads();

  // phase 2: wave wv owns h-tile wv
  f32x4 acc2 = {0.f, 0.f, 0.f, 0.f};
  int h = wv * 16 + l15;
  for (int s = 0; s < 32; ++s) {
    int f = flags[2 * s] | ((2 * s + 1 < 63) ? flags[2 * s + 1] : 0);
    if (!f) continue;
    bf16x8 a = *reinterpret_cast<bf16x8*>(W + l15 * SW + s * 32 + quad * 8);
    bf16x8 bfr = *reinterpret_cast<const bf16x8*>(GT + (size_t)h * 1024 + s * 32 + quad * 8);
    acc2 = __builtin_amdgcn_mfma_f32_16x16x32_bf16(a, bfr, acc2, 0, 0, 0);
  }
  #pragma unroll
  for (int r = 0; r < 4; ++r) {
    int row = quad * 4 + r;
    int gi = i0 + row;
    float inv = 1.f / fmaxf(rsum[row], 1e-30f);
    if (gi < 1000) ph[(size_t)gi * 128 + h] = acc2[r] * inv;
  }
}

// ---------------- final: out[b,c] = fc_b + sum_h relu(img_h[b,h]+ph[c,h]) * fc_w[h] ----------------
// 64x64 tiles, 512 blocks, 256 threads
__global__ __launch_bounds__(256) void final_k(
    const float* __restrict__ img_h, const float* __restrict__ ph,
    const float* __restrict__ fc_w, const float* __restrict__ fc_b,
    float* __restrict__ out) {
  __shared__ float ih[64][132];
  __shared__ float ps[64][132];
  __shared__ float ws_[128];
  int tid = threadIdx.x;
  int b0 = blockIdx.x * 64;
  int c0 = blockIdx.y * 64;
  for (int idx = tid; idx < 2048; idx += 256) {
    int row = idx >> 5, c4 = (idx & 31) * 4;
    float4 v = *reinterpret_cast<const float4*>(img_h + (size_t)(b0 + row) * 128 + c4);
    *reinterpret_cast<float4*>(&ih[row][c4]) = v;
  }
  for (int idx = tid; idx < 2048; idx += 256) {
    int row = idx >> 5, c4 = (idx & 31) * 4;
    int c = c0 + row;
    float4 v = make_float4(0.f, 0.f, 0.f, 0.f);
    if (c < 1000) v = *reinterpret_cast<const float4*>(ph + (size_t)c * 128 + c4);
    *reinterpret_cast<float4*>(&ps[row][c4]) = v;
  }
  if (tid < 128) ws_[tid] = fc_w[tid];
  __syncthreads();
  int tx = tid & 15, ty = tid >> 4;   // ty 0..15 -> 4 b-rows; tx -> 4 c-cols
  f32x2 acc[4][4] = {};
  const f32x2 zero2 = {0.f, 0.f};
  for (int h = 0; h < 128; h += 4) {
    float4 w4 = *reinterpret_cast<float4*>(&ws_[h]);
    f32x2 wlo = {w4.x, w4.y}, whi = {w4.z, w4.w};
    float4 a4[4], p4[4];
    #pragma unroll
    for (int i = 0; i < 4; ++i) a4[i] = *reinterpret_cast<float4*>(&ih[ty * 4 + i][h]);
    #pragma unroll
    for (int j = 0; j < 4; ++j) p4[j] = *reinterpret_cast<float4*>(&ps[tx * 4 + j][h]);
    #pragma unroll
    for (int i = 0; i < 4; ++i) {
      f32x2 alo = {a4[i].x, a4[i].y}, ahi = {a4[i].z, a4[i].w};
      #pragma unroll
      for (int j = 0; j < 4; ++j) {
        f32x2 plo = {p4[j].x, p4[j].y}, phi = {p4[j].z, p4[j].w};
        f32x2 t0 = __builtin_elementwise_max(alo + plo, zero2);
        f32x2 t1 = __builtin_elementwise_max(ahi + phi, zero2);
        acc[i][j] = acc[i][j] + t0 * wlo;
        acc[i][j] = acc[i][j] + t1 * whi;
      }
    }
  }
  float fb = fc_b[0];
  #pragma unroll
  for (int i = 0; i < 4; ++i) {
    int b = b0 + ty * 4 + i;
    int c = c0 + tx * 4;
    if (c < 1000) {
      float4 v = make_float4(acc[i][0].x + acc[i][0].y + fb, acc[i][1].x + acc[i][1].y + fb,
                             acc[i][2].x + acc[i][2].y + fb, acc[i][3].x + acc[i][3].y + fb);
      *reinterpret_cast<float4*>(out + (size_t)b * 1000 + c) = v;
    }
  }
}

extern "C" void kernel_launch(void* const* d_in, const int* in_sizes, int n_in,
                              void* d_out, int out_size, void* d_ws, size_t ws_size,
                              hipStream_t stream) {
  const float* image_feats = (const float*)d_in[0];   // [2048,2048]
  const float* img_proto   = (const float*)d_in[1];   // [1000,2048]
  const float* attributes  = (const float*)d_in[2];   // [1000,312]
  const float* att_g   = (const float*)d_in[4];       // [312,128]
  const float* slim_w  = (const float*)d_in[5];       // [2048,312]
  const float* slim_b  = (const float*)d_in[6];       // [312]
  const float* img_w   = (const float*)d_in[7];       // [2048,128]
  const float* proto_w = (const float*)d_in[8];       // [624,128]
  const float* proto_b = (const float*)d_in[9];       // [1,128]
  const float* fc_w    = (const float*)d_in[10];      // [128,1]
  const float* fc_b    = (const float*)d_in[11];      // [1]
  float* out = (float*)d_out;                         // [2048,1000]

  char* ws = (char*)d_ws;
  size_t o = 0;
  auto alloc = [&](size_t bytes) { size_t r = o; o += (bytes + 255) & ~(size_t)255; return r; };
  ushort_t* gn_bf   = (ushort_t*)(ws + alloc(1008ull * 128 * 2));   // normalized g bf16, tail zero
  ushort_t* M2T     = (ushort_t*)(ws + alloc(128ull * 2048 * 2));   // (slim_w @ proto_w2)^T bf16
  ushort_t* GT      = (ushort_t*)(ws + alloc(128ull * 1024 * 2));   // G^T + biasG, bf16
  float* biasG     = (float*)(ws + alloc(128ull * 4));              // slim_b@proto_w2 + proto_b
  float* ihp       = (float*)(ws + alloc(16ull * 2048 * 128 * 4));  // img_h split-K16 partials
  float* GT_part   = (float*)(ws + alloc(17ull * 128 * 1024 * 4));  // GT split-K partials (attr + 16 chunks)
  float* img_h     = (float*)(ws + alloc(2048ull * 128 * 4));
  float* ph        = (float*)(ws + alloc(1000ull * 128 * 4));

  // gn MFMA (8) + misc (1) + ihp x16 (256) + M2T (16) + GT0 (8) = 289
  prep_k<<<289, 256, 0, stream>>>(attributes, att_g, gn_bf,
                                  image_feats, img_w, ihp,
                                  proto_w, slim_w, M2T, GT_part,
                                  slim_b, proto_b, biasG);

  // img_h reduce (128, 16 chunks) + GT chunks 1..16 (128, K=128 each)
  red_k<<<256, 256, 0, stream>>>(ihp, img_h, M2T, img_proto, GT_part);

  // GT reduce + bias fold (17 chunks)
  gtred_k<<<32, 256, 0, stream>>>(GT_part, biasG, GT);

  // sim -> masked exp -> ph
  attn6_k<<<63, 512, 0, stream>>>(gn_bf, GT, ph);

  // relu-dot epilogue
  final_k<<<dim3(32, 16), 256, 0, stream>>>(img_h, ph, fc_w, fc_b, out);
}

// Round 11
// 153.659 us; speedup vs baseline: 1.0563x; 1.0563x over previous
//
#include <hip/hip_runtime.h>

typedef unsigned short ushort_t;
typedef __bf16 bf16x8 __attribute__((ext_vector_type(8)));
typedef float f32x4 __attribute__((ext_vector_type(4)));
typedef float f32x2 __attribute__((ext_vector_type(2)));
typedef ushort_t us4 __attribute__((ext_vector_type(4)));

#define T_SOFT 32.0f
#define THRESH 0.76604444311897803f   // cos(40 deg)
#define SW 1048                       // W strip LDS row stride (bf16)
#define SA 72                         // GEMM LDS row stride (bf16)

__device__ __forceinline__ ushort_t f2bf(float f) {
  union { float f; unsigned u; } x; x.f = f;
  unsigned r = (x.u + 0x7fffu + ((x.u >> 16) & 1u)) >> 16;  // RNE
  return (ushort_t)r;
}
__device__ __forceinline__ float bf2f(ushort_t h) {
  union { unsigned u; float f; } x; x.u = ((unsigned)h) << 16; return x.f;
}

// pack 4 fp32 -> 4 bf16
__device__ __forceinline__ us4 pack4(float4 x) {
  union { unsigned u[2]; us4 h; } r;
  union { float4 f; unsigned u[4]; } a;
  a.f = x;
  r.u[0] = __builtin_amdgcn_perm(a.u[1] + 0x8000u, a.u[0] + 0x8000u, 0x07060302u);
  r.u[1] = __builtin_amdgcn_perm(a.u[3] + 0x8000u, a.u[2] + 0x8000u, 0x07060302u);
  return r.h;
}

// ---- row-stage split load/store: rows clamped, cols >= climit -> 0 ----
struct RL { float4 v[8]; };
__device__ __forceinline__ RL r_load(const float* __restrict__ src, int srs, int rowbase, int rowmax,
                                     int kbase, int climit, int tid) {
  RL o;
  int frow = tid >> 4, fk = (tid & 15) * 4;
  #pragma unroll
  for (int p = 0; p < 8; ++p) {
    int row = rowbase + frow + p * 16; if (row > rowmax) row = rowmax;
    int k = kbase + fk;
    float4 val = make_float4(0.f, 0.f, 0.f, 0.f);
    if (k < climit) val = *reinterpret_cast<const float4*>(src + (size_t)row * srs + k);
    o.v[p] = val;
  }
  return o;
}
__device__ __forceinline__ void r_store(const RL& o, ushort_t* __restrict__ dst, int tid) {
  int frow = tid >> 4, fk = (tid & 15) * 4;
  #pragma unroll
  for (int p = 0; p < 8; ++p)
    *reinterpret_cast<us4*>(dst + (size_t)(frow + p * 16) * SA + fk) = pack4(o.v[p]);
}

// ---- transpose-stage split: dst[ncol][krow] <- src[rbase+krow][nbase+ncol]; rows>=rlimit -> 0 ----
struct TL { float v[4][8]; };
__device__ __forceinline__ TL t_load(const float* __restrict__ src, int srs, int rbase, int rlimit,
                                     int nbase, int tid) {
  TL o;
  int kg = (tid >> 4) * 4, ns = (tid & 15) * 8;
  #pragma unroll
  for (int i = 0; i < 4; ++i) {
    int r = rbase + kg + i;
    float4 a = make_float4(0.f,0.f,0.f,0.f), c = make_float4(0.f,0.f,0.f,0.f);
    if (r < rlimit) {
      a = *reinterpret_cast<const float4*>(src + (size_t)r * srs + nbase + ns);
      c = *reinterpret_cast<const float4*>(src + (size_t)r * srs + nbase + ns + 4);
    }
    o.v[i][0]=a.x; o.v[i][1]=a.y; o.v[i][2]=a.z; o.v[i][3]=a.w;
    o.v[i][4]=c.x; o.v[i][5]=c.y; o.v[i][6]=c.z; o.v[i][7]=c.w;
  }
  return o;
}
__device__ __forceinline__ void t_store(const TL& o, ushort_t* __restrict__ dst, int tid) {
  int kg = (tid >> 4) * 4, ns = (tid & 15) * 8;
  #pragma unroll
  for (int j = 0; j < 8; ++j) {
    us4 w;
    w[0] = f2bf(o.v[0][j]); w[1] = f2bf(o.v[1][j]); w[2] = f2bf(o.v[2][j]); w[3] = f2bf(o.v[3][j]);
    *reinterpret_cast<us4*>(dst + (size_t)(ns + j) * SA + kg) = w;
  }
}

// ---- bf16 row-stage split ----
struct AL { bf16x8 v[4]; };
__device__ __forceinline__ AL a_load(const ushort_t* __restrict__ src, int srs, int kbase, int tid) {
  AL o;
  int hrow = tid >> 3, hk = (tid & 7) * 8;
  #pragma unroll
  for (int p = 0; p < 4; ++p)
    o.v[p] = *reinterpret_cast<const bf16x8*>(src + (size_t)(hrow + p * 32) * srs + kbase + hk);
  return o;
}
__device__ __forceinline__ void a_store(const AL& o, ushort_t* __restrict__ dst, int tid) {
  int hrow = tid >> 3, hk = (tid & 7) * 8;
  #pragma unroll
  for (int p = 0; p < 4; ++p)
    *reinterpret_cast<bf16x8*>(dst + (size_t)(hrow + p * 32) * SA + hk) = o.v[p];
}

// ---- one 128x128x64 MFMA step over staged As/Bs ----
__device__ __forceinline__ void mfma8(ushort_t* __restrict__ As, ushort_t* __restrict__ Bs,
                                      int tid, f32x4 acc[2][8]) {
  int lane = tid & 63, wv = tid >> 6;
  int l15 = lane & 15, quad = lane >> 4;
  #pragma unroll
  for (int kh = 0; kh < 2; ++kh) {
    bf16x8 af[2];
    #pragma unroll
    for (int pi = 0; pi < 2; ++pi)
      af[pi] = *reinterpret_cast<bf16x8*>(As + ((wv * 2 + pi) * 16 + l15) * SA + kh * 32 + quad * 8);
    #pragma unroll
    for (int ct = 0; ct < 8; ++ct) {
      bf16x8 bfr = *reinterpret_cast<bf16x8*>(Bs + (ct * 16 + l15) * SA + kh * 32 + quad * 8);
      acc[0][ct] = __builtin_amdgcn_mfma_f32_16x16x32_bf16(af[0], bfr, acc[0][ct], 0, 0, 0);
      acc[1][ct] = __builtin_amdgcn_mfma_f32_16x16x32_bf16(af[1], bfr, acc[1][ct], 0, 0, 0);
    }
  }
}

// ---------------- prep: gn MFMA (8) + misc (1) + ihp x8 (128) + M2T (16) + GT0 (8) = 161 ----------------
__global__ __launch_bounds__(256) void prep_k(
    const float* __restrict__ attributes, const float* __restrict__ att_g,
    ushort_t* __restrict__ gn_bf,
    const float* __restrict__ image_feats, const float* __restrict__ img_w,
    float* __restrict__ ihp,
    const float* __restrict__ proto_w, const float* __restrict__ slim_w,
    ushort_t* __restrict__ M2T, float* __restrict__ GT_part,
    const float* __restrict__ slim_b, const float* __restrict__ proto_b,
    float* __restrict__ biasG) {
  __shared__ ushort_t As[128 * SA];
  __shared__ ushort_t Bs[128 * SA];
  int b = blockIdx.x, tid = threadIdx.x;
  if (b == 8) {                 // misc: zero gn tail rows 1000..1007 + biasG
    us4 z = {0, 0, 0, 0};
    *reinterpret_cast<us4*>(gn_bf + 1000 * 128 + tid * 4) = z;
    if (tid < 128) {
      int h = tid;
      float acc = proto_b[h];
      for (int n = 0; n < 312; n += 4) {
        acc += slim_b[n + 0] * proto_w[(size_t)(312 + n) * 128 + h];
        acc += slim_b[n + 1] * proto_w[(size_t)(313 + n) * 128 + h];
        acc += slim_b[n + 2] * proto_w[(size_t)(314 + n) * 128 + h];
        acc += slim_b[n + 3] * proto_w[(size_t)(315 + n) * 128 + h];
      }
      biasG[h] = acc;
    }
    return;
  }
  int lane = tid & 63, wv = tid >> 6;
  int l15 = lane & 15, quad = lane >> 4;
  f32x4 acc[2][8];
  #pragma unroll
  for (int i = 0; i < 2; ++i)
    #pragma unroll
    for (int j = 0; j < 8; ++j) acc[i][j] = f32x4{0.f, 0.f, 0.f, 0.f};

  if (b < 8) {                  // gn: g = attributes @ att_g (K=312->320), row-normalize, bf16
    int j0 = b * 128;
    RL ra = r_load(attributes, 312, j0, 999, 0, 312, tid);
    TL tb = t_load(att_g, 128, 0, 312, 0, tid);
    for (int s = 0; s < 5; ++s) {
      if (s) __syncthreads();
      r_store(ra, As, tid);
      t_store(tb, Bs, tid);
      if (s + 1 < 5) {
        ra = r_load(attributes, 312, j0, 999, (s + 1) * 64, 312, tid);
        tb = t_load(att_g, 128, (s + 1) * 64, 312, 0, tid);
      }
      __syncthreads();
      mfma8(As, Bs, tid, acc);
    }
    // per-row sumsq: for fixed (wv,pi,quad,r) the 16 lanes (l15) x 8 ct tiles cover all 128 cols
    #pragma unroll
    for (int pi = 0; pi < 2; ++pi)
      #pragma unroll
      for (int r = 0; r < 4; ++r) {
        float ss = 0.f;
        #pragma unroll
        for (int ct = 0; ct < 8; ++ct) ss += acc[pi][ct][r] * acc[pi][ct][r];
        ss += __shfl_xor(ss, 1, 64); ss += __shfl_xor(ss, 2, 64);
        ss += __shfl_xor(ss, 4, 64); ss += __shfl_xor(ss, 8, 64);
        float inv = 1.f / fmaxf(sqrtf(ss), 1e-12f);
        int row = j0 + (wv * 2 + pi) * 16 + quad * 4 + r;
        if (row < 1000) {
          #pragma unroll
          for (int ct = 0; ct < 8; ++ct)
            gn_bf[(size_t)row * 128 + ct * 16 + l15] = f2bf(acc[pi][ct][r] * inv);
        }
      }
    return;
  }

  if (b < 137) {                // ihp split-K8 partial: b in [9,137) -> 128 blocks
    int q = b - 9;
    int tile = q >> 3, kc = q & 7;
    int r0 = tile * 128, k0 = kc * 256;
    RL ra = r_load(image_feats, 2048, r0, 2047, k0, 1 << 30, tid);
    TL tb = t_load(img_w, 128, k0, 2048, 0, tid);
    #pragma unroll
    for (int s = 0; s < 4; ++s) {
      if (s) __syncthreads();
      r_store(ra, As, tid);
      t_store(tb, Bs, tid);
      if (s + 1 < 4) {
        ra = r_load(image_feats, 2048, r0, 2047, k0 + (s + 1) * 64, 1 << 30, tid);
        tb = t_load(img_w, 128, k0 + (s + 1) * 64, 2048, 0, tid);
      }
      __syncthreads();
      mfma8(As, Bs, tid, acc);
    }
    float* Cp = ihp + (size_t)kc * 262144;
    #pragma unroll
    for (int pi = 0; pi < 2; ++pi)
      #pragma unroll
      for (int ct = 0; ct < 8; ++ct) {
        int col = ct * 16 + l15;
        #pragma unroll
        for (int r = 0; r < 4; ++r) {
          int row = r0 + (wv * 2 + pi) * 16 + quad * 4 + r;
          Cp[(size_t)row * 128 + col] = acc[pi][ct][r];
        }
      }
    return;
  }
  if (b < 153) {                // M2T: b in [137,153) -> 16 blocks
    int c0 = (b - 137) * 128;
    TL ta = t_load(proto_w, 128, 312, 624, 0, tid);
    RL rb = r_load(slim_w, 312, c0, 2047, 0, 312, tid);
    for (int s = 0; s < 5; ++s) {
      if (s) __syncthreads();
      t_store(ta, As, tid);
      r_store(rb, Bs, tid);
      if (s + 1 < 5) {
        ta = t_load(proto_w, 128, 312 + (s + 1) * 64, 624, 0, tid);
        rb = r_load(slim_w, 312, c0, 2047, (s + 1) * 64, 312, tid);
      }
      __syncthreads();
      mfma8(As, Bs, tid, acc);
    }
    #pragma unroll
    for (int pi = 0; pi < 2; ++pi)
      #pragma unroll
      for (int ct = 0; ct < 8; ++ct) {
        int col = c0 + ct * 16 + l15;
        #pragma unroll
        for (int r = 0; r < 4; ++r) {
          int row = (wv * 2 + pi) * 16 + quad * 4 + r;
          M2T[(size_t)row * 2048 + col] = f2bf(acc[pi][ct][r]);
        }
      }
    return;
  }
  {                             // GT0: b in [153,161) -> 8 blocks; GT0[h][j] = sum_n proto_w[n][h]*attributes[j][n]
    int j0 = (b - 153) * 128;
    TL ta = t_load(proto_w, 128, 0, 312, 0, tid);
    RL rb = r_load(attributes, 312, j0, 999, 0, 312, tid);
    for (int s = 0; s < 5; ++s) {
      if (s) __syncthreads();
      t_store(ta, As, tid);
      r_store(rb, Bs, tid);
      if (s + 1 < 5) {
        ta = t_load(proto_w, 128, (s + 1) * 64, 312, 0, tid);
        rb = r_load(attributes, 312, j0, 999, (s + 1) * 64, 312, tid);
      }
      __syncthreads();
      mfma8(As, Bs, tid, acc);
    }
    #pragma unroll
    for (int pi = 0; pi < 2; ++pi)
      #pragma unroll
      for (int ct = 0; ct < 8; ++ct) {
        int col = j0 + ct * 16 + l15;
        #pragma unroll
        for (int r = 0; r < 4; ++r) {
          int row = (wv * 2 + pi) * 16 + quad * 4 + r;
          GT_part[(size_t)row * 1024 + col] = acc[pi][ct][r];
        }
      }
  }
}

// ---------------- red: img_h reduce (128) + GT chunks 1..8 partials (64, K=256) = 192 ----------------
__global__ __launch_bounds__(256) void red_k(
    const float* __restrict__ ihp, float* __restrict__ img_h,
    const ushort_t* __restrict__ M2T, const float* __restrict__ img_proto,
    float* __restrict__ GT_part) {
  __shared__ ushort_t As[128 * SA];
  __shared__ ushort_t Bs[128 * SA];
  int b = blockIdx.x, tid = threadIdx.x;
  if (b < 128) {                // img_h[r][h] = sum_{c<8} ihp[c][r][h]
    int t = b * 256 + tid;      // 0..32767
    size_t base = (size_t)t * 8;
    #pragma unroll
    for (int g = 0; g < 2; ++g) {
      float4 s = *reinterpret_cast<const float4*>(ihp + base + g * 4);
      #pragma unroll
      for (int c = 1; c < 8; ++c) {
        float4 v = *reinterpret_cast<const float4*>(ihp + (size_t)c * 262144 + base + g * 4);
        s.x += v.x; s.y += v.y; s.z += v.z; s.w += v.w;
      }
      *reinterpret_cast<float4*>(img_h + base + g * 4) = s;
    }
    return;
  }
  int q = b - 128;              // 0..63
  int jt = q >> 3, ch = q & 7;
  int j0 = jt * 128, k0 = ch * 256;
  f32x4 acc[2][8];
  #pragma unroll
  for (int i = 0; i < 2; ++i)
    #pragma unroll
    for (int j = 0; j < 8; ++j) acc[i][j] = f32x4{0.f, 0.f, 0.f, 0.f};
  AL aa = a_load(M2T, 2048, k0, tid);
  RL rb = r_load(img_proto, 2048, j0, 999, k0, 1 << 30, tid);
  #pragma unroll
  for (int s = 0; s < 4; ++s) {
    if (s) __syncthreads();
    a_store(aa, As, tid);
    r_store(rb, Bs, tid);
    if (s + 1 < 4) {
      aa = a_load(M2T, 2048, k0 + (s + 1) * 64, tid);
      rb = r_load(img_proto, 2048, j0, 999, k0 + (s + 1) * 64, 1 << 30, tid);
    }
    __syncthreads();
    mfma8(As, Bs, tid, acc);
  }
  int lane = tid & 63, wv = tid >> 6;
  int l15 = lane & 15, quad = lane >> 4;
  float* dst = GT_part + (size_t)(ch + 1) * 131072;
  #pragma unroll
  for (int pi = 0; pi < 2; ++pi)
    #pragma unroll
    for (int ct = 0; ct < 8; ++ct) {
      int col = j0 + ct * 16 + l15;
      #pragma unroll
      for (int r = 0; r < 4; ++r) {
        int row = (wv * 2 + pi) * 16 + quad * 4 + r;
        dst[(size_t)row * 1024 + col] = acc[pi][ct][r];
      }
    }
}

// ---------------- gtred: GT = bf16( sum_{c<9} GT_part[c] + biasG[h] ) ----------------
__global__ __launch_bounds__(256) void gtred_k(const float* __restrict__ GT_part,
                                               const float* __restrict__ biasG,
                                               ushort_t* __restrict__ GT) {
  int t = blockIdx.x * 256 + threadIdx.x;   // 0..8191
  size_t base = (size_t)t * 16;
  int row = (int)(base >> 10);
  float bg = biasG[row];
  #pragma unroll
  for (int g = 0; g < 4; ++g) {
    float4 s = *reinterpret_cast<const float4*>(GT_part + base + g * 4);
    #pragma unroll
    for (int c = 1; c < 9; ++c) {
      float4 v = *reinterpret_cast<const float4*>(GT_part + (size_t)c * 131072 + base + g * 4);
      s.x += v.x; s.y += v.y; s.z += v.z; s.w += v.w;
    }
    s.x += bg; s.y += bg; s.z += bg; s.w += bg;
    *reinterpret_cast<us4*>(GT + base + g * 4) = pack4(s);
  }
}

// ---------------- attn6: sim -> masked exp -> ph = (W@GT^T)/rsum ; 512 threads ----------------
__global__ __launch_bounds__(512) void attn6_k(
    const ushort_t* __restrict__ gn_bf, const ushort_t* __restrict__ GT,
    float* __restrict__ ph) {
  __shared__ ushort_t W[16 * SW];
  __shared__ float rsum[16];
  __shared__ int flags[63];
  int tid = threadIdx.x;
  int i0 = blockIdx.x * 16;
  int lane = tid & 63, wv = tid >> 6;       // wv 0..7
  int l15 = lane & 15, quad = lane >> 4;
  if (tid < 63) flags[tid] = 0;
  if (tid >= 64 && tid < 80) rsum[tid - 64] = 0.f;
  if (tid < 256) W[(tid >> 4) * SW + 1008 + (tid & 15)] = 0;   // zero k-pad cols 1008..1023
  __syncthreads();

  const ushort_t* abase = gn_bf + (size_t)(i0 + l15) * 128 + quad * 8;
  bf16x8 af0 = *reinterpret_cast<const bf16x8*>(abase);
  bf16x8 af1 = *reinterpret_cast<const bf16x8*>(abase + 32);
  bf16x8 af2 = *reinterpret_cast<const bf16x8*>(abase + 64);
  bf16x8 af3 = *reinterpret_cast<const bf16x8*>(abase + 96);
  float rs[4] = {0.f, 0.f, 0.f, 0.f};
  for (int jt = wv; jt < 63; jt += 8) {
    const ushort_t* bbase = gn_bf + (size_t)(jt * 16 + l15) * 128 + quad * 8;
    f32x4 d = {0.f, 0.f, 0.f, 0.f};
    d = __builtin_amdgcn_mfma_f32_16x16x32_bf16(af0, *reinterpret_cast<const bf16x8*>(bbase),      d, 0, 0, 0);
    d = __builtin_amdgcn_mfma_f32_16x16x32_bf16(af1, *reinterpret_cast<const bf16x8*>(bbase + 32), d, 0, 0, 0);
    d = __builtin_amdgcn_mfma_f32_16x16x32_bf16(af2, *reinterpret_cast<const bf16x8*>(bbase + 64), d, 0, 0, 0);
    d = __builtin_amdgcn_mfma_f32_16x16x32_bf16(af3, *reinterpret_cast<const bf16x8*>(bbase + 96), d, 0, 0, 0);
    int hot = 0;
    #pragma unroll
    for (int r = 0; r < 4; ++r) {
      float w = 0.f;
      if (d[r] > THRESH) { w = __expf(T_SOFT * (d[r] - 1.0f)); hot = 1; }
      ushort_t wb = f2bf(w);
      W[(quad * 4 + r) * SW + jt * 16 + l15] = wb;
      rs[r] += bf2f(wb);
    }
    if (hot) flags[jt] = 1;
  }
  #pragma unroll
  for (int r = 0; r < 4; ++r) {
    float v = rs[r];
    v += __shfl_xor(v, 1, 64); v += __shfl_xor(v, 2, 64);
    v += __shfl_xor(v, 4, 64); v += __shfl_xor(v, 8, 64);
    if (l15 == 0) atomicAdd(&rsum[quad * 4 + r], v);
  }
  __syncthreads();

  // phase 2: wave wv owns h-tile wv
  f32x4 acc2 = {0.f, 0.f, 0.f, 0.f};
  int h = wv * 16 + l15;
  for (int s = 0; s < 32; ++s) {
    int f = flags[2 * s] | ((2 * s + 1 < 63) ? flags[2 * s + 1] : 0);
    if (!f) continue;
    bf16x8 a = *reinterpret_cast<bf16x8*>(W + l15 * SW + s * 32 + quad * 8);
    bf16x8 bfr = *reinterpret_cast<const bf16x8*>(GT + (size_t)h * 1024 + s * 32 + quad * 8);
    acc2 = __builtin_amdgcn_mfma_f32_16x16x32_bf16(a, bfr, acc2, 0, 0, 0);
  }
  #pragma unroll
  for (int r = 0; r < 4; ++r) {
    int row = quad * 4 + r;
    int gi = i0 + row;
    float inv = 1.f / fmaxf(rsum[row], 1e-30f);
    if (gi < 1000) ph[(size_t)gi * 128 + h] = acc2[r] * inv;
  }
}

// ---------------- final: out[b,c] = fc_b + sum_h relu(img_h[b,h]+ph[c,h]) * fc_w[h] ----------------
// 64x64 tiles, 512 blocks, 256 threads
__global__ __launch_bounds__(256) void final_k(
    const float* __restrict__ img_h, const float* __restrict__ ph,
    const float* __restrict__ fc_w, const float* __restrict__ fc_b,
    float* __restrict__ out) {
  __shared__ float ih[64][132];
  __shared__ float ps[64][132];
  __shared__ float ws_[128];
  int tid = threadIdx.x;
  int b0 = blockIdx.x * 64;
  int c0 = blockIdx.y * 64;
  for (int idx = tid; idx < 2048; idx += 256) {
    int row = idx >> 5, c4 = (idx & 31) * 4;
    float4 v = *reinterpret_cast<const float4*>(img_h + (size_t)(b0 + row) * 128 + c4);
    *reinterpret_cast<float4*>(&ih[row][c4]) = v;
  }
  for (int idx = tid; idx < 2048; idx += 256) {
    int row = idx >> 5, c4 = (idx & 31) * 4;
    int c = c0 + row;
    float4 v = make_float4(0.f, 0.f, 0.f, 0.f);
    if (c < 1000) v = *reinterpret_cast<const float4*>(ph + (size_t)c * 128 + c4);
    *reinterpret_cast<float4*>(&ps[row][c4]) = v;
  }
  if (tid < 128) ws_[tid] = fc_w[tid];
  __syncthreads();
  int tx = tid & 15, ty = tid >> 4;   // ty 0..15 -> 4 b-rows; tx -> 4 c-cols
  f32x2 acc[4][4] = {};
  const f32x2 zero2 = {0.f, 0.f};
  for (int h = 0; h < 128; h += 4) {
    float4 w4 = *reinterpret_cast<float4*>(&ws_[h]);
    f32x2 wlo = {w4.x, w4.y}, whi = {w4.z, w4.w};
    float4 a4[4], p4[4];
    #pragma unroll
    for (int i = 0; i < 4; ++i) a4[i] = *reinterpret_cast<float4*>(&ih[ty * 4 + i][h]);
    #pragma unroll
    for (int j = 0; j < 4; ++j) p4[j] = *reinterpret_cast<float4*>(&ps[tx * 4 + j][h]);
    #pragma unroll
    for (int i = 0; i < 4; ++i) {
      f32x2 alo = {a4[i].x, a4[i].y}, ahi = {a4[i].z, a4[i].w};
      #pragma unroll
      for (int j = 0; j < 4; ++j) {
        f32x2 plo = {p4[j].x, p4[j].y}, phi = {p4[j].z, p4[j].w};
        f32x2 t0 = __builtin_elementwise_max(alo + plo, zero2);
        f32x2 t1 = __builtin_elementwise_max(ahi + phi, zero2);
        acc[i][j] = acc[i][j] + t0 * wlo;
        acc[i][j] = acc[i][j] + t1 * whi;
      }
    }
  }
  float fb = fc_b[0];
  #pragma unroll
  for (int i = 0; i < 4; ++i) {
    int b = b0 + ty * 4 + i;
    int c = c0 + tx * 4;
    if (c < 1000) {
      float4 v = make_float4(acc[i][0].x + acc[i][0].y + fb, acc[i][1].x + acc[i][1].y + fb,
                             acc[i][2].x + acc[i][2].y + fb, acc[i][3].x + acc[i][3].y + fb);
      *reinterpret_cast<float4*>(out + (size_t)b * 1000 + c) = v;
    }
  }
}

extern "C" void kernel_launch(void* const* d_in, const int* in_sizes, int n_in,
                              void* d_out, int out_size, void* d_ws, size_t ws_size,
                              hipStream_t stream) {
  const float* image_feats = (const float*)d_in[0];   // [2048,2048]
  const float* img_proto   = (const float*)d_in[1];   // [1000,2048]
  const float* attributes  = (const float*)d_in[2];   // [1000,312]
  const float* att_g   = (const float*)d_in[4];       // [312,128]
  const float* slim_w  = (const float*)d_in[5];       // [2048,312]
  const float* slim_b  = (const float*)d_in[6];       // [312]
  const float* img_w   = (const float*)d_in[7];       // [2048,128]
  const float* proto_w = (const float*)d_in[8];       // [624,128]
  const float* proto_b = (const float*)d_in[9];       // [1,128]
  const float* fc_w    = (const float*)d_in[10];      // [128,1]
  const float* fc_b    = (const float*)d_in[11];      // [1]
  float* out = (float*)d_out;                         // [2048,1000]

  char* ws = (char*)d_ws;
  size_t o = 0;
  auto alloc = [&](size_t bytes) { size_t r = o; o += (bytes + 255) & ~(size_t)255; return r; };
  ushort_t* gn_bf   = (ushort_t*)(ws + alloc(1008ull * 128 * 2));   // normalized g bf16, tail zero
  ushort_t* M2T     = (ushort_t*)(ws + alloc(128ull * 2048 * 2));   // (slim_w @ proto_w2)^T bf16
  ushort_t* GT      = (ushort_t*)(ws + alloc(128ull * 1024 * 2));   // G^T + biasG, bf16
  float* biasG     = (float*)(ws + alloc(128ull * 4));              // slim_b@proto_w2 + proto_b
  float* ihp       = (float*)(ws + alloc(8ull * 2048 * 128 * 4));   // img_h split-K8 partials
  float* GT_part   = (float*)(ws + alloc(9ull * 128 * 1024 * 4));   // GT split-K partials (attr + 8 chunks)
  float* img_h     = (float*)(ws + alloc(2048ull * 128 * 4));
  float* ph        = (float*)(ws + alloc(1000ull * 128 * 4));

  // gn MFMA (8) + misc (1) + ihp x8 (128) + M2T (16) + GT0 (8) = 161
  prep_k<<<161, 256, 0, stream>>>(attributes, att_g, gn_bf,
                                  image_feats, img_w, ihp,
                                  proto_w, slim_w, M2T, GT_part,
                                  slim_b, proto_b, biasG);

  // img_h reduce (128) + GT chunks 1..8 (64, K=256 each)
  red_k<<<192, 256, 0, stream>>>(ihp, img_h, M2T, img_proto, GT_part);

  // GT reduce + bias fold (9 chunks)
  gtred_k<<<32, 256, 0, stream>>>(GT_part, biasG, GT);

  // sim -> masked exp -> ph
  attn6_k<<<63, 512, 0, stream>>>(gn_bf, GT, ph);

  // relu-dot epilogue
  final_k<<<dim3(32, 16), 256, 0, stream>>>(img_h, ph, fc_w, fc_b, out);
}